// Round 2
// baseline (591.584 us; speedup 1.0000x reference)
//
#include <hip/hip_runtime.h>

// SigJoin (Chen's identity), D=8, M=6, BATCH=128.
// z_K[j] = x_K[j] + y[j&7] * S,  S = sum_{i=0}^{K-1} x_i[j>>3(K-i)] * Q_i / (K-i)!
// Factorization used here: S(g) = x_{K-1}[g] + sy[g&7] * R(g>>3), R shared by the
// whole octet of groups with equal prefix. Level start offsets LOFF[k]:
// 0, 8, 72, 584, 4680, 37448.
//
// Block roles (grid.x = 39, grid.y = row):
//   bx  0..31 : level 6, 4 groups (32 floats) per thread, shared-R
//   bx 32..35 : level 5, 4 groups per thread, shared-R
//   bx 36..38 : levels 1-4, 1 group (8 floats) per thread, generic chain
// Loads are cached (NOT nontemporal) so consecutive 16B chunks of a 64B line
// hit L1; stores are nontemporal (output never re-read).

#define SIGLEN 299592

typedef float v4f __attribute__((ext_vector_type(4)));

__device__ constexpr float INV_FACT[8] = {1.f, 1.f, 0.5f, 1.f/6.f, 1.f/24.f,
                                          1.f/120.f, 1.f/720.f, 1.f/5040.f};
__device__ constexpr int LOFF[7] = {0, 0, 8, 72, 584, 4680, 37448};

// Full chain for a single group (levels 1-4 fallback path).
template<int K>
__device__ __forceinline__ float prefix_S(const float* __restrict__ xrow,
                                          const float* sy, int col) {
    int tt = (col - LOFF[K]) >> 3;
    float S = 0.f, Q = 1.f;
#pragma unroll
    for (int i = K - 1; i >= 1; --i) {
        S += xrow[LOFF[i] + tt] * (INV_FACT[K - i] * Q);
        Q *= sy[tt & 7];
        tt >>= 3;
    }
    S += Q * INV_FACT[K];
    return S;
}

// Shared tail: R(h) such that S(g) = x_{K-1}[g] + sy[g&7] * R(g>>3).
template<int K>
__device__ __forceinline__ float R_chain(const float* __restrict__ xrow,
                                         const float* sy, int h) {
    float R = 0.f, Q = 1.f;
#pragma unroll
    for (int i = K - 2; i >= 1; --i) {
        R += xrow[LOFF[i] + h] * (INV_FACT[K - i] * Q);
        Q *= sy[h & 7];
        h >>= 3;
    }
    return R + Q * INV_FACT[K];
}

__device__ __forceinline__ float S_group(const float* __restrict__ xrow,
                                         const float* sy, int col) {
    if      (col >=  584) return prefix_S<4>(xrow, sy, col);
    else if (col >=   72) return prefix_S<3>(xrow, sy, col);
    else if (col >=    8) return prefix_S<2>(xrow, sy, col);
    else                  return 1.f;   // level 1: z = x + y
}

// Process 4 consecutive groups (32 floats) at local group base s4 (s4 % 4 == 0,
// s4 & 7 in {0,4}) of level K. col = global element index of group s4's start.
template<int K>
__device__ __forceinline__ void do_quad(const float* __restrict__ xrow,
                                        float* __restrict__ orow,
                                        const float* sy, int s4, int col) {
    const float R = R_chain<K>(xrow, sy, s4 >> 3);
    const v4f xk  = *(const v4f*)(xrow + LOFF[K - 1] + s4);    // 4 prefixes, contiguous
    const v4f syd = *(const v4f*)(&sy[s4 & 4]);                // digits d..d+3
    const v4f S   = xk + syd * R;

    v4f xs[8];
#pragma unroll
    for (int k = 0; k < 8; ++k)
        xs[k] = *(const v4f*)(xrow + col + 4 * k);             // 128B cached read

    const v4f ya = *(const v4f*)(&sy[0]);
    const v4f yb = *(const v4f*)(&sy[4]);
#pragma unroll
    for (int j = 0; j < 4; ++j) {
        __builtin_nontemporal_store(xs[2*j]     + S[j] * ya, (v4f*)(orow + col + 8*j));
        __builtin_nontemporal_store(xs[2*j + 1] + S[j] * yb, (v4f*)(orow + col + 8*j + 4));
    }
}

__global__ __launch_bounds__(256) void sigjoin_kernel(
    const float* __restrict__ x, const float* __restrict__ y,
    float* __restrict__ out)
{
    __shared__ float sy[8];
    const int row = blockIdx.y;
    const int tid = threadIdx.x;
    if (tid < 8) sy[tid] = y[row * 8 + tid];
    __syncthreads();

    const float* __restrict__ xrow = x   + (size_t)row * SIGLEN;
    float* __restrict__       orow = out + (size_t)row * SIGLEN;
    const int bx = blockIdx.x;

    if (bx < 32) {
        // level 6: 32768 groups, 4/thread, 32 blocks exactly
        const int s4  = (bx * 256 + tid) * 4;
        const int col = 37448 + s4 * 8;
        do_quad<6>(xrow, orow, sy, s4, col);
    } else if (bx < 36) {
        // level 5: 4096 groups, 4/thread, 4 blocks exactly
        const int s4  = ((bx - 32) * 256 + tid) * 4;
        const int col = 4680 + s4 * 8;
        do_quad<5>(xrow, orow, sy, s4, col);
    } else {
        // levels 1-4: 585 groups, 1 group (8 floats) per thread, 3 blocks
        const int g = (bx - 36) * 256 + tid;
        if (g >= 585) return;
        const int col = g * 8;
        const float S = S_group(xrow, sy, col);
        const v4f xa = *(const v4f*)(xrow + col);
        const v4f xb = *(const v4f*)(xrow + col + 4);
        const v4f ya = *(const v4f*)(&sy[0]);
        const v4f yb = *(const v4f*)(&sy[4]);
        __builtin_nontemporal_store(xa + S * ya, (v4f*)(orow + col));
        __builtin_nontemporal_store(xb + S * yb, (v4f*)(orow + col + 4));
    }
}

extern "C" void kernel_launch(void* const* d_in, const int* in_sizes, int n_in,
                              void* d_out, int out_size, void* d_ws, size_t ws_size,
                              hipStream_t stream) {
    const float* x = (const float*)d_in[0];
    const float* y = (const float*)d_in[1];
    float* out = (float*)d_out;

    dim3 grid(39, 128, 1);     // 32 (L6) + 4 (L5) + 3 (L1-4) block roles per row
    dim3 block(256, 1, 1);
    hipLaunchKernelGGL(sigjoin_kernel, grid, block, 0, stream, x, y, out);
}

// Round 4
// 255.882 us; speedup vs baseline: 2.3119x; 2.3119x over previous
//
#include <hip/hip_runtime.h>

// SigJoin (Chen's identity), D=8, M=6, BATCH=128.
// z_K[j] = x_K[j] + y[j&7] * S,  S = sum_{i=0}^{K-1} x_i[j>>3(K-i)] * Q_i / (K-i)!
// (x_0 = 1). Level start offsets (element space): 0, 8, 72, 584, 4680, 37448.
//
// Round-2 lesson (rocprof): WRITE_SIZE was 3.4x ideal (521 MB vs 153 MB) because
// stores were 16B pieces at 128B lane stride with the nontemporal hint -- lines
// never merged before eviction. This version makes every load/store instruction
// WAVE-CONTIGUOUS: one float4 per thread, lane l covers base + 16*l, so each
// store instruction writes 16 complete 64B lines (1 KB contiguous). The per-lane
// scalar prefix chain is free (VALUBusy was 0.46%); prefix loads are L1/L2 hits.

#define SIGLEN 299592
#define NCHUNK (SIGLEN / 4)   // 74898 float4 chunks per row (exact)

typedef float v4f __attribute__((ext_vector_type(4)));

__device__ constexpr float INV_FACT[8] = {1.f, 1.f, 0.5f, 1.f/6.f, 1.f/24.f,
                                          1.f/120.f, 1.f/720.f, 1.f/5040.f};
__device__ constexpr int LOFF[7] = {0, 0, 8, 72, 584, 4680, 37448};

// Prefix chain for the group containing element col at level K.
template<int K>
__device__ __forceinline__ float prefix_S(const float* __restrict__ xrow,
                                          const float* sy, int col) {
    int tt = (col - LOFF[K]) >> 3;   // prefix index at level K-1
    float S = 0.f, Q = 1.f;
#pragma unroll
    for (int i = K - 1; i >= 1; --i) {
        S += xrow[LOFF[i] + tt] * (INV_FACT[K - i] * Q);
        Q *= sy[tt & 7];
        tt >>= 3;
    }
    S += Q * INV_FACT[K];            // e_K term (x_0 = 1)
    return S;
}

__global__ __launch_bounds__(256) void sigjoin_kernel(
    const float* __restrict__ x, const float* __restrict__ y,
    float* __restrict__ out)
{
    __shared__ float sy[8];
    const int row = blockIdx.y;
    const int tid = threadIdx.x;
    if (tid < 8) sy[tid] = y[row * 8 + tid];
    __syncthreads();

    const int c = blockIdx.x * 256 + tid;   // one float4 chunk per thread
    if (c >= NCHUNK) return;
    const int col = c * 4;                  // wave-contiguous: lane l at +16B*l

    const float* __restrict__ xrow = x   + (size_t)row * SIGLEN;
    float* __restrict__       orow = out + (size_t)row * SIGLEN;

    float S;
    if      (col >= 37448) S = prefix_S<6>(xrow, sy, col);
    else if (col >=  4680) S = prefix_S<5>(xrow, sy, col);
    else if (col >=   584) S = prefix_S<4>(xrow, sy, col);
    else if (col >=    72) S = prefix_S<3>(xrow, sy, col);
    else if (col >=     8) S = prefix_S<2>(xrow, sy, col);
    else                   S = 1.f;   // level 1: z = x + y

    const v4f xa = *(const v4f*)(xrow + col);          // cached, 1KB/instr/wave
    const v4f yh = *(const v4f*)(&sy[col & 4]);        // digits 0-3 or 4-7
    const v4f za = xa + S * yh;
    __builtin_nontemporal_store(za, (v4f*)(orow + col)); // full-line coalesced
}

extern "C" void kernel_launch(void* const* d_in, const int* in_sizes, int n_in,
                              void* d_out, int out_size, void* d_ws, size_t ws_size,
                              hipStream_t stream) {
    const float* x = (const float*)d_in[0];
    const float* y = (const float*)d_in[1];
    float* out = (float*)d_out;

    const int bx = (NCHUNK + 255) / 256;   // 293 blocks per row
    dim3 grid(bx, 128, 1);
    dim3 block(256, 1, 1);
    hipLaunchKernelGGL(sigjoin_kernel, grid, block, 0, stream, x, y, out);
}